// Round 8
// baseline (1149.429 us; speedup 1.0000x reference)
//
#include <hip/hip_runtime.h>

// ---------------------------------------------------------------------------
// RNN_69526930588180: 3-layer SimpleRNN (tanh), B=256, T=256, D=64, H=512.
//
// Round 22 = round 21 RESUBMITTED (infra failure, no data): round 16 EXACTLY
// (best-known 1020-1079us PASS) with ONE change: SPLIT ACCUMULATORS in the
// K16 MFMA pipe (even kt -> acc, odd kt -> acd).
//  * Clock-corrected model (r20 post-mortem): MfmaUtil 6.8% x 320 MFMA-busy
//    cy/SIMD/step => step ~= 4700 cy; wall 4.03us/step => chip runs ~1.17GHz
//    (power-managed at 7% util). At 4700cy the chain model fits, and the
//    dominant term is MFMA DEPENDENCY STALLS: 4 acc chains re-issue every
//    ~20cy vs ~24-32cy MFMA latency -> 64 MFMAs cost ~2000cy not ~320.
//  * Fix: 8 independent chains (acc[0..3] + acd[0..3]); dependent reissue
//    spacing 40cy > latency -> issue-bound. Merge acc+acd in the epilogue
//    (combine/tanh for rec, Cbuf write for proj). +16 VGPRs, 1 wave/SIMD.
//  * Sync/store fabric untouched (r17/r18/r19/r20 all proved neutral/bad).
// ---------------------------------------------------------------------------

typedef unsigned short u16;
typedef unsigned int   u32;
typedef unsigned long long u64;

typedef __attribute__((ext_vector_type(8))) short short8;
typedef __attribute__((ext_vector_type(4))) float f32x4;
typedef __attribute__((ext_vector_type(4))) int   i32x4;

#define N_B 256
#define N_T 256
#define N_D 64
#define N_H 512
#define LAY 3
#define BG  8     // batch groups (32 rows each) == XCD buckets
#define CGS 8     // col groups (64 cols each)
#define ROWS 32   // rows per bg
#define WCOL 64   // cols per WG
#define NWG (LAY * BG * CGS)   // 192
#define CNT_TGT 8    // 8 WGs publish once per (layer,bg,t)
#define CPAD 16      // u32 per counter (64B line)
#define CNT_LINES (LAY * BG * N_T)
#define XBASE (CNT_LINES * CPAD)      // arrive counter line
#define XCCS  (XBASE + CPAD)          // 192-entry xcc array
#define CNT_U32 (XCCS + NWG)
#define SPIN_LIM (1u << 22)

__device__ __forceinline__ u16 f2bf(float f) {
  union { float f; u32 u; } v; v.f = f;
  u32 u = v.u;
  u += 0x7fffu + ((u >> 16) & 1u);   // RNE
  return (u16)(u >> 16);
}
__device__ __forceinline__ float bf2f(u16 h) {
  union { u32 u; float f; } v; v.u = ((u32)h) << 16;
  return v.f;
}
__device__ __forceinline__ short8 ld8(const u16* p) { return *(const short8*)p; }
__device__ __forceinline__ short8 cvt8(const float* p) {
  short8 r;
#pragma unroll
  for (int j = 0; j < 8; ++j) r[j] = (short)f2bf(p[j]);
  return r;
}
__device__ __forceinline__ short8 as_s8(i32x4 v) {
  union { i32x4 i; short8 s; } u; u.i = v; return u.s;
}
__device__ __forceinline__ float fast_tanh(float x) {
  float xc = fminf(fmaxf(x, -9.f), 9.f);
  float e  = __builtin_amdgcn_exp2f(xc * 2.8853900817779268f);
  return 1.f - 2.f * __builtin_amdgcn_rcpf(e + 1.f);
}
// FIFO-fair coherence-point read (r6/r9/r13-proven). The ONLY safe poll.
__device__ __forceinline__ u32 rmw_read(u32* p) {
  u32 v, z = 0;
  asm volatile("global_atomic_add %0, %1, %2, off sc0\n\ts_waitcnt vmcnt(0)"
               : "=v"(v) : "v"(p), "v"(z) : "memory");
  return v;
}
// Global counter poll (lane0 of one wave only).
__device__ __forceinline__ void poll_cnt(u32* cp, u32 target, bool fast, bool* dead) {
  u32 it = 0;
  for (;;) {
    u32 v = fast ? rmw_read(cp)
                 : __hip_atomic_load(cp, __ATOMIC_RELAXED, __HIP_MEMORY_SCOPE_AGENT);
    if (v >= target) return;
    if (it >= 2) __builtin_amdgcn_s_sleep(1);
    if (++it > SPIN_LIM) { *dead = true; return; }
  }
}
// Single-line RMW poll (startup barrier only).
__device__ __forceinline__ void poll_one(u32* cp, u32 target, bool* dead) {
  u32 it = 0;
  while (rmw_read(cp) < target) {
    __builtin_amdgcn_s_sleep(1);
    if (++it > SPIN_LIM) { *dead = true; return; }
  }
}
// LDS flag ops (CU-coherent): set / spin-until-equal.
__device__ __forceinline__ void lds_set(volatile u32* f, u32 v) {
  __hip_atomic_store((u32*)f, v, __ATOMIC_RELEASE, __HIP_MEMORY_SCOPE_WORKGROUP);
}
__device__ __forceinline__ void lds_wait(volatile u32* f, u32 want, bool* dead) {
  u32 it = 0;
  while (__hip_atomic_load((u32*)f, __ATOMIC_ACQUIRE, __HIP_MEMORY_SCOPE_WORKGROUP) != want) {
    if (++it > SPIN_LIM) { *dead = true; return; }
  }
}

// 16 batched A-fragment loads (row fixed, k = kt*32 + quad*8), ASYNC: no
// trailing vmcnt. Consumers use counted waits tied to each fragment.
__device__ __forceinline__ void load16_async_fast(const u16* p, i32x4 f[16]) {
  asm volatile(
      "global_load_dwordx4 %0, %16, off sc0\n\t"
      "global_load_dwordx4 %1, %16, off offset:64 sc0\n\t"
      "global_load_dwordx4 %2, %16, off offset:128 sc0\n\t"
      "global_load_dwordx4 %3, %16, off offset:192 sc0\n\t"
      "global_load_dwordx4 %4, %16, off offset:256 sc0\n\t"
      "global_load_dwordx4 %5, %16, off offset:320 sc0\n\t"
      "global_load_dwordx4 %6, %16, off offset:384 sc0\n\t"
      "global_load_dwordx4 %7, %16, off offset:448 sc0\n\t"
      "global_load_dwordx4 %8, %16, off offset:512 sc0\n\t"
      "global_load_dwordx4 %9, %16, off offset:576 sc0\n\t"
      "global_load_dwordx4 %10, %16, off offset:640 sc0\n\t"
      "global_load_dwordx4 %11, %16, off offset:704 sc0\n\t"
      "global_load_dwordx4 %12, %16, off offset:768 sc0\n\t"
      "global_load_dwordx4 %13, %16, off offset:832 sc0\n\t"
      "global_load_dwordx4 %14, %16, off offset:896 sc0\n\t"
      "global_load_dwordx4 %15, %16, off offset:960 sc0"
      : "=&v"(f[0]), "=&v"(f[1]), "=&v"(f[2]), "=&v"(f[3]),
        "=&v"(f[4]), "=&v"(f[5]), "=&v"(f[6]), "=&v"(f[7]),
        "=&v"(f[8]), "=&v"(f[9]), "=&v"(f[10]), "=&v"(f[11]),
        "=&v"(f[12]), "=&v"(f[13]), "=&v"(f[14]), "=&v"(f[15])
      : "v"(p) : "memory");
}
__device__ __forceinline__ void load16_async_slow(const u16* p, i32x4 f[16]) {
  asm volatile(
      "global_load_dwordx4 %0, %16, off sc0 sc1\n\t"
      "global_load_dwordx4 %1, %16, off offset:64 sc0 sc1\n\t"
      "global_load_dwordx4 %2, %16, off offset:128 sc0 sc1\n\t"
      "global_load_dwordx4 %3, %16, off offset:192 sc0 sc1\n\t"
      "global_load_dwordx4 %4, %16, off offset:256 sc0 sc1\n\t"
      "global_load_dwordx4 %5, %16, off offset:320 sc0 sc1\n\t"
      "global_load_dwordx4 %6, %16, off offset:384 sc0 sc1\n\t"
      "global_load_dwordx4 %7, %16, off offset:448 sc0 sc1\n\t"
      "global_load_dwordx4 %8, %16, off offset:512 sc0 sc1\n\t"
      "global_load_dwordx4 %9, %16, off offset:576 sc0 sc1\n\t"
      "global_load_dwordx4 %10, %16, off offset:640 sc0 sc1\n\t"
      "global_load_dwordx4 %11, %16, off offset:704 sc0 sc1\n\t"
      "global_load_dwordx4 %12, %16, off offset:768 sc0 sc1\n\t"
      "global_load_dwordx4 %13, %16, off offset:832 sc0 sc1\n\t"
      "global_load_dwordx4 %14, %16, off offset:896 sc0 sc1\n\t"
      "global_load_dwordx4 %15, %16, off offset:960 sc0 sc1"
      : "=&v"(f[0]), "=&v"(f[1]), "=&v"(f[2]), "=&v"(f[3]),
        "=&v"(f[4]), "=&v"(f[5]), "=&v"(f[6]), "=&v"(f[7]),
        "=&v"(f[8]), "=&v"(f[9]), "=&v"(f[10]), "=&v"(f[11]),
        "=&v"(f[12]), "=&v"(f[13]), "=&v"(f[14]), "=&v"(f[15])
      : "v"(p) : "memory");
}

#define MFMA16(a, b, c) __builtin_amdgcn_mfma_f32_16x16x32_bf16((a), (b), (c), 0, 0, 0)

// One K-subtile into accumulator set D (acc for even kt, acd for odd kt):
// 8 independent chains -> dependent reissue spacing 40cy > MFMA latency.
#define STEPK(kt, N, D)                                                     \
  do {                                                                      \
    asm volatile("s_waitcnt vmcnt(" #N ")" : "+v"(fr[kt]) :: "memory");     \
    short8 a_ = as_s8(fr[kt]);                                              \
    D[0] = MFMA16(a_, wf[kt][0], D[0]);                                     \
    D[1] = MFMA16(a_, wf[kt][1], D[1]);                                     \
    D[2] = MFMA16(a_, wf[kt][2], D[2]);                                     \
    D[3] = MFMA16(a_, wf[kt][3], D[3]);                                     \
  } while (0)
#define K16_PIPE()                                                          \
  STEPK(0, 15, acc); STEPK(1, 14, acd); STEPK(2, 13, acc); STEPK(3, 12, acd); \
  STEPK(4, 11, acc); STEPK(5, 10, acd); STEPK(6, 9, acc);  STEPK(7, 8, acd);  \
  STEPK(8, 7, acc);  STEPK(9, 6, acd);  STEPK(10, 5, acc); STEPK(11, 4, acd); \
  STEPK(12, 3, acc); STEPK(13, 2, acd); STEPK(14, 1, acc); STEPK(15, 0, acd)

// All 3 layers in one persistent kernel (layer-wavefront pipeline).
__global__ __launch_bounds__(256, 1)
void rnn_pipe(const float* __restrict__ x,
              const float* __restrict__ Wx0, const float* __restrict__ Wh0, const float* __restrict__ b0,
              const float* __restrict__ Wx1, const float* __restrict__ Wh1, const float* __restrict__ b1,
              const float* __restrict__ Wx2, const float* __restrict__ Wh2, const float* __restrict__ b2,
              u16* __restrict__ seq0, u16* __restrict__ seq1, u16* __restrict__ seq2,
              u32* __restrict__ cnt) {
  const int tid  = threadIdx.x;
  const int lane = tid & 63;
  const int w    = tid >> 6;                // 0-1 rec, 2-3 proj
  const int quad = lane >> 4;
  const int l16  = lane & 15;
  const int half = w & 1;                   // 16-row sub-tile
  const bool is_rec = (w < 2);

  __shared__ u16   WhT[WCOL][N_H];     // [n][k], k rotated by 8*n (staging only)
  __shared__ u16   WxT[WCOL][N_H];     // layer0 uses only [.][0..63]
  __shared__ float Cbuf[2][ROWS][WCOL + 1];
  __shared__ u32   sflags[6];          // [0..1] rec-rdy par, [2..3] proj-rdy par, [4..5] pub par
  __shared__ u32   sx[NWG];            // startup: xcc per block
  __shared__ u32   sbar;               // startup barrier result

  u32* arrive = cnt + XBASE;
  u32* xccs   = cnt + XCCS;

  // ---- startup: publish placement, global barrier, deterministic replay ----
  u32 xcc;
  asm volatile("s_getreg_b32 %0, hwreg(HW_REG_XCC_ID)" : "=s"(xcc));
  if (tid == 0) {
    u32* xe = xccs + blockIdx.x;
    u32 xv = xcc & 7u;
    asm volatile("global_store_dword %0, %1, off sc0 sc1\n\ts_waitcnt vmcnt(0)"
                 :: "v"(xe), "v"(xv) : "memory");
    __hip_atomic_fetch_add(arrive, 1u, __ATOMIC_RELAXED, __HIP_MEMORY_SCOPE_AGENT);
    bool bd = false;
    poll_one(arrive, (u32)NWG, &bd);
    sbar = bd ? 1u : 0u;
  }
  if (tid < 6) sflags[tid] = 0;
  __syncthreads();
  const bool bar_dead = (sbar != 0);
  if (!bar_dead && tid < NWG) sx[tid] = rmw_read(xccs + tid) & 7u;
  __syncthreads();

  int bg, layer, j; bool fast;
  if (bar_dead) {
    bg = blockIdx.x & 7;
    int rst = blockIdx.x >> 3;
    layer = rst >> 3; j = rst & 7;
    fast = false;
  } else {
    // replay arrivals: bucket x = the 24 roles of batch-group x. Native
    // claims fill slots 0..23; overflow takes unfilled slots in order.
    u64 c64 = 0;                 // 8x 8-bit native-claim counts (capped at 24)
    int myrid = -1, mypend = -1, pends = 0;
    for (int i = 0; i < NWG; ++i) {
      u32 xv = sx[i];
      u32 c = (u32)((c64 >> (8u * xv)) & 0xffu);
      if (c < 24u) {
        if (i == (int)blockIdx.x) myrid = (int)(xv * 24u + c);
        c64 += (1ull << (8u * xv));
      } else {
        if (i == (int)blockIdx.x) mypend = pends;
        ++pends;
      }
    }
    if (myrid < 0) {
      int p = 0;
      for (int xb = 0; xb < 8; ++xb) {
        u32 c = (u32)((c64 >> (8u * xb)) & 0xffu);
        for (u32 s = c; s < 24u; ++s) {
          if (p == mypend) myrid = xb * 24 + (int)s;
          ++p;
        }
      }
    }
    bg = myrid / 24;
    int slot = myrid % 24;
    layer = slot >> 3; j = slot & 7;
    fast = (((c64 >> (8u * (u32)bg)) & 0xffu) >= 24u);  // all 24 slots native
  }
  const int b = bg;

  const float *Wx, *Wh, *bias; const u16 *in_seq = nullptr; u16 *out_seq;
  if (layer == 0)      { Wx = Wx0; Wh = Wh0; bias = b0; out_seq = seq0; }
  else if (layer == 1) { Wx = Wx1; Wh = Wh1; bias = b1; in_seq = seq0; out_seq = seq1; }
  else                 { Wx = Wx2; Wh = Wh2; bias = b2; in_seq = seq1; out_seq = seq2; }
  const int kin = (layer == 0) ? N_D : N_H;
  u32* cnt_own  = cnt + (size_t)(layer * BG + b) * N_T * CPAD;
  u32* cnt_prev = (layer > 0) ? cnt + (size_t)((layer - 1) * BG + b) * N_T * CPAD : nullptr;

  // Stage weight slices (cols j*64..+64).
  for (int e = tid; e < WCOL * N_H; e += 256) {
    int n = e & 63, k = e >> 6;
    WhT[n][(k + 8 * n) & (N_H - 1)] = f2bf(Wh[k * N_H + j * WCOL + n]);
  }
  for (int e = tid; e < WCOL * kin; e += 256) {
    int n = e & 63, k = e >> 6;
    WxT[n][(k + 8 * n) & (kin - 1)] = f2bf(Wx[k * N_H + j * WCOL + n]);
  }
  float bv[4];
#pragma unroll
  for (int n = 0; n < 4; ++n) bv[n] = bias[j * WCOL + n * 16 + l16];
  __syncthreads();

  // ---- one-time: pull this wave's B fragments from LDS into REGISTERS ----
  // Same array for every role -> single live range. Static indexing (rule #20).
  short8 wf[16][4];
  if (is_rec) {
#pragma unroll
    for (int kt = 0; kt < 16; ++kt)
#pragma unroll
      for (int n = 0; n < 4; ++n) {
        int nl = n * 16 + l16;
        wf[kt][n] = ld8(&WhT[nl][(kt * 32 + quad * 8 + 8 * nl) & (N_H - 1)]);
      }
  } else if (layer == 0) {
#pragma unroll
    for (int n = 0; n < 4; ++n) {
      int nl = n * 16 + l16;
      wf[0][n] = ld8(&WxT[nl][(quad * 8 + 8 * nl) & (N_D - 1)]);
      wf[1][n] = ld8(&WxT[nl][(32 + quad * 8 + 8 * nl) & (N_D - 1)]);
    }
  } else {
#pragma unroll
    for (int kt = 0; kt < 16; ++kt)
#pragma unroll
      for (int n = 0; n < 4; ++n) {
        int nl = n * 16 + l16;
        wf[kt][n] = ld8(&WxT[nl][(kt * 32 + quad * 8 + 8 * nl) & (N_H - 1)]);
      }
  }

  const int arow = b * ROWS + half * 16 + l16;  // this lane's A-row
  bool dead = false;

  for (int t = 0; t < N_T; ++t) {
    const int par = t & 1;
    f32x4 acc[4] = {{0.f,0.f,0.f,0.f},{0.f,0.f,0.f,0.f},{0.f,0.f,0.f,0.f},{0.f,0.f,0.f,0.f}};
    f32x4 acd[4] = {{0.f,0.f,0.f,0.f},{0.f,0.f,0.f,0.f},{0.f,0.f,0.f,0.f},{0.f,0.f,0.f,0.f}};

    if (!is_rec) {
      // ---- proj waves: (layer0: x_t@Wx) / (else: h_{l-1}(t)@Wx) -> Cbuf ----
      if (layer == 0) {
        const float* xp = x + ((size_t)arow * N_T + t) * N_D + quad * 8;
        short8 f0 = cvt8(xp), f1 = cvt8(xp + 32);
#pragma unroll
        for (int n = 0; n < 4; ++n) {
          acc[n] = MFMA16(f0, wf[0][n], acc[n]);
          acd[n] = MFMA16(f1, wf[1][n], acd[n]);
        }
      } else {
        // ONE poller (w2); w3 spins on LDS flag.
        if (half == 0) {
          if (lane == 0) {
            if (!dead) poll_cnt(cnt_prev + (size_t)t * CPAD, CNT_TGT, fast, &dead);
            lds_set(&sflags[2 + par], (u32)(t + 1));
          }
        } else {
          if (lane == 0 && !dead) lds_wait(&sflags[2 + par], (u32)(t + 1), &dead);
        }
        const u16* sp = in_seq + ((size_t)t * N_B + arow) * N_H + quad * 8;
        i32x4 fr[16];
        if (fast) load16_async_fast(sp, fr);
        else      load16_async_slow(sp, fr);
        K16_PIPE();
      }
      // write proj partials (merged acc+acd) to Cbuf[par]
      int rb = half * 16 + quad * 4;
#pragma unroll
      for (int n = 0; n < 4; ++n)
#pragma unroll
        for (int r = 0; r < 4; ++r)
          Cbuf[par][rb + r][n * 16 + l16] = acc[n][r] + acd[n][r];
    } else {
      // ---- rec waves: wait own layer t-1 (ONE poller: wave0), load A, h@Wh ----
      if (t > 0) {
        if (half == 0) {
          if (lane == 0) {
            if (!dead) poll_cnt(cnt_own + (size_t)(t - 1) * CPAD, CNT_TGT, fast, &dead);
            lds_set(&sflags[par], (u32)t);
          }
        } else {
          if (lane == 0 && !dead) lds_wait(&sflags[par], (u32)t, &dead);
        }
        const u16* ap = out_seq + ((size_t)(t - 1) * N_B + arow) * N_H + quad * 8;
        i32x4 fr[16];
        if (fast) load16_async_fast(ap, fr);
        else      load16_async_slow(ap, fr);
        K16_PIPE();
      }
    }

    __syncthreads();  // the only per-step barrier: Cbuf[par] ready

    if (is_rec) {
      // ---- combine + tanh + store h; ONE publish per WG ----
      int rb = half * 16 + quad * 4;
      u32 hv[4][4];
#pragma unroll
      for (int n = 0; n < 4; ++n)
#pragma unroll
        for (int r = 0; r < 4; ++r)
          hv[n][r] = (u32)f2bf(fast_tanh(acc[n][r] + acd[n][r]
                                         + Cbuf[par][rb + r][n * 16 + l16] + bv[n]));
      // lane addr: row = b*32 + half*16 + quad*4 (+r), col = j*64 + l16 (+n*16)
      u16* hdst = out_seq + ((size_t)t * N_B + b * ROWS + half * 16 + quad * 4) * N_H
                  + j * WCOL + l16;
      if (fast) {
        asm volatile(
            "global_store_short %0, %1, off sc0\n\t"
            "global_store_short %0, %2, off offset:1024 sc0\n\t"
            "global_store_short %0, %3, off offset:2048 sc0\n\t"
            "global_store_short %0, %4, off offset:3072 sc0\n\t"
            "global_store_short %0, %5, off offset:32 sc0\n\t"
            "global_store_short %0, %6, off offset:1056 sc0\n\t"
            "global_store_short %0, %7, off offset:2080 sc0\n\t"
            "global_store_short %0, %8, off offset:3104 sc0\n\t"
            "global_store_short %0, %9, off offset:64 sc0\n\t"
            "global_store_short %0, %10, off offset:1088 sc0\n\t"
            "global_store_short %0, %11, off offset:2112 sc0\n\t"
            "global_store_short %0, %12, off offset:3136 sc0\n\t"
            "global_store_short %0, %13, off offset:96 sc0\n\t"
            "global_store_short %0, %14, off offset:1120 sc0\n\t"
            "global_store_short %0, %15, off offset:2144 sc0\n\t"
            "global_store_short %0, %16, off offset:3168 sc0"
            :: "v"(hdst),
               "v"(hv[0][0]), "v"(hv[0][1]), "v"(hv[0][2]), "v"(hv[0][3]),
               "v"(hv[1][0]), "v"(hv[1][1]), "v"(hv[1][2]), "v"(hv[1][3]),
               "v"(hv[2][0]), "v"(hv[2][1]), "v"(hv[2][2]), "v"(hv[2][3]),
               "v"(hv[3][0]), "v"(hv[3][1]), "v"(hv[3][2]), "v"(hv[3][3])
            : "memory");
      } else {
        asm volatile(
            "global_store_short %0, %1, off sc0 sc1\n\t"
            "global_store_short %0, %2, off offset:1024 sc0 sc1\n\t"
            "global_store_short %0, %3, off offset:2048 sc0 sc1\n\t"
            "global_store_short %0, %4, off offset:3072 sc0 sc1\n\t"
            "global_store_short %0, %5, off offset:32 sc0 sc1\n\t"
            "global_store_short %0, %6, off offset:1056 sc0 sc1\n\t"
            "global_store_short %0, %7, off offset:2080 sc0 sc1\n\t"
            "global_store_short %0, %8, off offset:3104 sc0 sc1\n\t"
            "global_store_short %0, %9, off offset:64 sc0 sc1\n\t"
            "global_store_short %0, %10, off offset:1088 sc0 sc1\n\t"
            "global_store_short %0, %11, off offset:2112 sc0 sc1\n\t"
            "global_store_short %0, %12, off offset:3136 sc0 sc1\n\t"
            "global_store_short %0, %13, off offset:96 sc0 sc1\n\t"
            "global_store_short %0, %14, off offset:1120 sc0 sc1\n\t"
            "global_store_short %0, %15, off offset:2144 sc0 sc1\n\t"
            "global_store_short %0, %16, off offset:3168 sc0 sc1"
            :: "v"(hdst),
               "v"(hv[0][0]), "v"(hv[0][1]), "v"(hv[0][2]), "v"(hv[0][3]),
               "v"(hv[1][0]), "v"(hv[1][1]), "v"(hv[1][2]), "v"(hv[1][3]),
               "v"(hv[2][0]), "v"(hv[2][1]), "v"(hv[2][2]), "v"(hv[2][3]),
               "v"(hv[3][0]), "v"(hv[3][1]), "v"(hv[3][2]), "v"(hv[3][3])
            : "memory");
      }
      asm volatile("s_waitcnt vmcnt(0)" ::: "memory");  // this wave's stores acked
      if (half == 1) {
        if (lane == 0) lds_set(&sflags[4 + par], (u32)(t + 1));   // wave1 drained
      } else {
        if (lane == 0) {
          if (!dead) lds_wait(&sflags[4 + par], (u32)(t + 1), &dead);  // both drained
          u32* cp = cnt_own + (size_t)t * CPAD;
          if (fast) {
            u32 one = 1u;
            asm volatile("global_atomic_add %0, %1, off" :: "v"(cp), "v"(one) : "memory");
          } else {
            __hip_atomic_fetch_add(cp, 1u, __ATOMIC_RELAXED, __HIP_MEMORY_SCOPE_AGENT);
          }
        }
      }
    }
    // no trailing barrier: Cbuf parity + next barrier handle WAR (r8/r9-proven)
  }
}

// out[b] = seq2[T-1][b][:] . Wf + bf
__global__ void head_kernel(const u16* __restrict__ seq2, const float* __restrict__ Wf,
                            const float* __restrict__ bf, float* __restrict__ out) {
  int b    = blockIdx.x;
  int lane = threadIdx.x;  // 64
  const u16* hrow = seq2 + ((size_t)(N_T - 1) * N_B + b) * N_H;
  float s = 0.f;
#pragma unroll
  for (int r = 0; r < N_H / 64; ++r) {
    int idx = lane * 8 + r;
    s += bf2f(hrow[idx]) * Wf[idx];
  }
#pragma unroll
  for (int off = 32; off > 0; off >>= 1) s += __shfl_down(s, off);
  if (lane == 0) out[b] = s + bf[0];
}

extern "C" void kernel_launch(void* const* d_in, const int* in_sizes, int n_in,
                              void* d_out, int out_size, void* d_ws, size_t ws_size,
                              hipStream_t stream) {
  const float* x   = (const float*)d_in[0];
  const float* Wx0 = (const float*)d_in[1];
  const float* Wh0 = (const float*)d_in[2];
  const float* b0  = (const float*)d_in[3];
  const float* Wx1 = (const float*)d_in[4];
  const float* Wh1 = (const float*)d_in[5];
  const float* b1  = (const float*)d_in[6];
  const float* Wx2 = (const float*)d_in[7];
  const float* Wh2 = (const float*)d_in[8];
  const float* b2  = (const float*)d_in[9];
  const float* Wf  = (const float*)d_in[10];
  const float* bf  = (const float*)d_in[11];
  float* out = (float*)d_out;

  const size_t SEQ_BYTES = (size_t)N_T * N_B * N_H * sizeof(u16);  // 67,108,864
  if (ws_size < 3 * SEQ_BYTES + (size_t)CNT_U32 * sizeof(u32)) return;

  char* ws  = (char*)d_ws;
  u16* seq0 = (u16*)(ws);
  u16* seq1 = (u16*)(ws + SEQ_BYTES);
  u16* seq2 = (u16*)(ws + 2 * SEQ_BYTES);
  u32* cnt  = (u32*)(ws + 3 * SEQ_BYTES);

  (void)hipMemsetAsync(cnt, 0, (size_t)CNT_U32 * sizeof(u32), stream);

  rnn_pipe<<<LAY * BG * CGS, 256, 0, stream>>>(x, Wx0, Wh0, b0, Wx1, Wh1, b1,
                                               Wx2, Wh2, b2, seq0, seq1, seq2,
                                               cnt);
  head_kernel<<<N_B, 64, 0, stream>>>(seq2, Wf, bf, out);
}

// Round 9
// 1068.686 us; speedup vs baseline: 1.0756x; 1.0756x over previous
//
#include <hip/hip_runtime.h>

// ---------------------------------------------------------------------------
// RNN_69526930588180: 3-layer SimpleRNN (tanh), B=256, T=256, D=64, H=512.
//
// Round 23 = round 16 EXACTLY (best-known 1020-1079us PASS) with ONE change:
// HOT-SPIN POLLING (no s_sleep until iteration 1024).
//  * Scorecard: 6 probes (counter sharding r17, load-poll r18, coalesced
//    stores r19, plain stores r20, XCD affinity r16, split acc r22) ALL
//    land 1020-1100us. The ~4us/step chain is pinned by something every
//    probe kept: the RMW poll with s_sleep(1) backoff at iteration>=2.
//  * Counter arithmetic: MfmaUtil 6.5% x 320 busy-cy => step ~4900cy at
//    ~1.2GHz; ~85% of the step is WAITING. Typical discovery takes >2 poll
//    iterations -> poller is ASLEEP when the counter lands. If s_sleep
//    wake-up is scheduler-requeue scale (100s of ns..us on a throttled CU),
//    every handoff eats 1-2 wake latencies = the 4us floor, and explains
//    why all fabric probes (which kept the sleep) were neutral.
//  * Fix: hot-spin RMW poll (s_sleep only after 1024 iterations as a
//    pathological fallback; SPIN_LIM deadman unchanged).
//  * Split-acc (r22) reverted: measured neutral-to-worse.
// ---------------------------------------------------------------------------

typedef unsigned short u16;
typedef unsigned int   u32;
typedef unsigned long long u64;

typedef __attribute__((ext_vector_type(8))) short short8;
typedef __attribute__((ext_vector_type(4))) float f32x4;
typedef __attribute__((ext_vector_type(4))) int   i32x4;

#define N_B 256
#define N_T 256
#define N_D 64
#define N_H 512
#define LAY 3
#define BG  8     // batch groups (32 rows each) == XCD buckets
#define CGS 8     // col groups (64 cols each)
#define ROWS 32   // rows per bg
#define WCOL 64   // cols per WG
#define NWG (LAY * BG * CGS)   // 192
#define CNT_TGT 8    // 8 WGs publish once per (layer,bg,t)
#define CPAD 16      // u32 per counter (64B line)
#define CNT_LINES (LAY * BG * N_T)
#define XBASE (CNT_LINES * CPAD)      // arrive counter line
#define XCCS  (XBASE + CPAD)          // 192-entry xcc array
#define CNT_U32 (XCCS + NWG)
#define SPIN_LIM (1u << 22)

__device__ __forceinline__ u16 f2bf(float f) {
  union { float f; u32 u; } v; v.f = f;
  u32 u = v.u;
  u += 0x7fffu + ((u >> 16) & 1u);   // RNE
  return (u16)(u >> 16);
}
__device__ __forceinline__ float bf2f(u16 h) {
  union { u32 u; float f; } v; v.u = ((u32)h) << 16;
  return v.f;
}
__device__ __forceinline__ short8 ld8(const u16* p) { return *(const short8*)p; }
__device__ __forceinline__ short8 cvt8(const float* p) {
  short8 r;
#pragma unroll
  for (int j = 0; j < 8; ++j) r[j] = (short)f2bf(p[j]);
  return r;
}
__device__ __forceinline__ short8 as_s8(i32x4 v) {
  union { i32x4 i; short8 s; } u; u.i = v; return u.s;
}
__device__ __forceinline__ float fast_tanh(float x) {
  float xc = fminf(fmaxf(x, -9.f), 9.f);
  float e  = __builtin_amdgcn_exp2f(xc * 2.8853900817779268f);
  return 1.f - 2.f * __builtin_amdgcn_rcpf(e + 1.f);
}
// FIFO-fair coherence-point read (r6/r9/r13-proven). The ONLY safe poll.
__device__ __forceinline__ u32 rmw_read(u32* p) {
  u32 v, z = 0;
  asm volatile("global_atomic_add %0, %1, %2, off sc0\n\ts_waitcnt vmcnt(0)"
               : "=v"(v) : "v"(p), "v"(z) : "memory");
  return v;
}
// Global counter poll (lane0 of one wave only). HOT SPIN: no sleep in the
// normal regime; sleep only after 1024 iterations (pathological fallback).
__device__ __forceinline__ void poll_cnt(u32* cp, u32 target, bool fast, bool* dead) {
  u32 it = 0;
  for (;;) {
    u32 v = fast ? rmw_read(cp)
                 : __hip_atomic_load(cp, __ATOMIC_RELAXED, __HIP_MEMORY_SCOPE_AGENT);
    if (v >= target) return;
    if (it >= 1024) __builtin_amdgcn_s_sleep(1);
    if (++it > SPIN_LIM) { *dead = true; return; }
  }
}
// Single-line RMW poll (startup barrier only).
__device__ __forceinline__ void poll_one(u32* cp, u32 target, bool* dead) {
  u32 it = 0;
  while (rmw_read(cp) < target) {
    __builtin_amdgcn_s_sleep(1);
    if (++it > SPIN_LIM) { *dead = true; return; }
  }
}
// LDS flag ops (CU-coherent): set / spin-until-equal.
__device__ __forceinline__ void lds_set(volatile u32* f, u32 v) {
  __hip_atomic_store((u32*)f, v, __ATOMIC_RELEASE, __HIP_MEMORY_SCOPE_WORKGROUP);
}
__device__ __forceinline__ void lds_wait(volatile u32* f, u32 want, bool* dead) {
  u32 it = 0;
  while (__hip_atomic_load((u32*)f, __ATOMIC_ACQUIRE, __HIP_MEMORY_SCOPE_WORKGROUP) != want) {
    if (++it > SPIN_LIM) { *dead = true; return; }
  }
}

// 16 batched A-fragment loads (row fixed, k = kt*32 + quad*8), ASYNC: no
// trailing vmcnt. Consumers use counted waits tied to each fragment.
__device__ __forceinline__ void load16_async_fast(const u16* p, i32x4 f[16]) {
  asm volatile(
      "global_load_dwordx4 %0, %16, off sc0\n\t"
      "global_load_dwordx4 %1, %16, off offset:64 sc0\n\t"
      "global_load_dwordx4 %2, %16, off offset:128 sc0\n\t"
      "global_load_dwordx4 %3, %16, off offset:192 sc0\n\t"
      "global_load_dwordx4 %4, %16, off offset:256 sc0\n\t"
      "global_load_dwordx4 %5, %16, off offset:320 sc0\n\t"
      "global_load_dwordx4 %6, %16, off offset:384 sc0\n\t"
      "global_load_dwordx4 %7, %16, off offset:448 sc0\n\t"
      "global_load_dwordx4 %8, %16, off offset:512 sc0\n\t"
      "global_load_dwordx4 %9, %16, off offset:576 sc0\n\t"
      "global_load_dwordx4 %10, %16, off offset:640 sc0\n\t"
      "global_load_dwordx4 %11, %16, off offset:704 sc0\n\t"
      "global_load_dwordx4 %12, %16, off offset:768 sc0\n\t"
      "global_load_dwordx4 %13, %16, off offset:832 sc0\n\t"
      "global_load_dwordx4 %14, %16, off offset:896 sc0\n\t"
      "global_load_dwordx4 %15, %16, off offset:960 sc0"
      : "=&v"(f[0]), "=&v"(f[1]), "=&v"(f[2]), "=&v"(f[3]),
        "=&v"(f[4]), "=&v"(f[5]), "=&v"(f[6]), "=&v"(f[7]),
        "=&v"(f[8]), "=&v"(f[9]), "=&v"(f[10]), "=&v"(f[11]),
        "=&v"(f[12]), "=&v"(f[13]), "=&v"(f[14]), "=&v"(f[15])
      : "v"(p) : "memory");
}
__device__ __forceinline__ void load16_async_slow(const u16* p, i32x4 f[16]) {
  asm volatile(
      "global_load_dwordx4 %0, %16, off sc0 sc1\n\t"
      "global_load_dwordx4 %1, %16, off offset:64 sc0 sc1\n\t"
      "global_load_dwordx4 %2, %16, off offset:128 sc0 sc1\n\t"
      "global_load_dwordx4 %3, %16, off offset:192 sc0 sc1\n\t"
      "global_load_dwordx4 %4, %16, off offset:256 sc0 sc1\n\t"
      "global_load_dwordx4 %5, %16, off offset:320 sc0 sc1\n\t"
      "global_load_dwordx4 %6, %16, off offset:384 sc0 sc1\n\t"
      "global_load_dwordx4 %7, %16, off offset:448 sc0 sc1\n\t"
      "global_load_dwordx4 %8, %16, off offset:512 sc0 sc1\n\t"
      "global_load_dwordx4 %9, %16, off offset:576 sc0 sc1\n\t"
      "global_load_dwordx4 %10, %16, off offset:640 sc0 sc1\n\t"
      "global_load_dwordx4 %11, %16, off offset:704 sc0 sc1\n\t"
      "global_load_dwordx4 %12, %16, off offset:768 sc0 sc1\n\t"
      "global_load_dwordx4 %13, %16, off offset:832 sc0 sc1\n\t"
      "global_load_dwordx4 %14, %16, off offset:896 sc0 sc1\n\t"
      "global_load_dwordx4 %15, %16, off offset:960 sc0 sc1"
      : "=&v"(f[0]), "=&v"(f[1]), "=&v"(f[2]), "=&v"(f[3]),
        "=&v"(f[4]), "=&v"(f[5]), "=&v"(f[6]), "=&v"(f[7]),
        "=&v"(f[8]), "=&v"(f[9]), "=&v"(f[10]), "=&v"(f[11]),
        "=&v"(f[12]), "=&v"(f[13]), "=&v"(f[14]), "=&v"(f[15])
      : "v"(p) : "memory");
}

#define MFMA16(a, b, c) __builtin_amdgcn_mfma_f32_16x16x32_bf16((a), (b), (c), 0, 0, 0)

// One K-subtile: wait until frag kt landed (in-order vmcnt; "+v" tie makes the
// MFMAs data-depend on the post-wait value so they cannot hoist above it),
// then 4 MFMAs from registers. Compiler-inserted VMEM ops can only over-wait.
#define STEPK(kt, N)                                                        \
  do {                                                                      \
    asm volatile("s_waitcnt vmcnt(" #N ")" : "+v"(fr[kt]) :: "memory");     \
    short8 a_ = as_s8(fr[kt]);                                              \
    acc[0] = MFMA16(a_, wf[kt][0], acc[0]);                                 \
    acc[1] = MFMA16(a_, wf[kt][1], acc[1]);                                 \
    acc[2] = MFMA16(a_, wf[kt][2], acc[2]);                                 \
    acc[3] = MFMA16(a_, wf[kt][3], acc[3]);                                 \
  } while (0)
#define K16_PIPE()                                                          \
  STEPK(0, 15); STEPK(1, 14); STEPK(2, 13); STEPK(3, 12);                   \
  STEPK(4, 11); STEPK(5, 10); STEPK(6, 9);  STEPK(7, 8);                    \
  STEPK(8, 7);  STEPK(9, 6);  STEPK(10, 5); STEPK(11, 4);                   \
  STEPK(12, 3); STEPK(13, 2); STEPK(14, 1); STEPK(15, 0)

// All 3 layers in one persistent kernel (layer-wavefront pipeline).
__global__ __launch_bounds__(256, 1)
void rnn_pipe(const float* __restrict__ x,
              const float* __restrict__ Wx0, const float* __restrict__ Wh0, const float* __restrict__ b0,
              const float* __restrict__ Wx1, const float* __restrict__ Wh1, const float* __restrict__ b1,
              const float* __restrict__ Wx2, const float* __restrict__ Wh2, const float* __restrict__ b2,
              u16* __restrict__ seq0, u16* __restrict__ seq1, u16* __restrict__ seq2,
              u32* __restrict__ cnt) {
  const int tid  = threadIdx.x;
  const int lane = tid & 63;
  const int w    = tid >> 6;                // 0-1 rec, 2-3 proj
  const int quad = lane >> 4;
  const int l16  = lane & 15;
  const int half = w & 1;                   // 16-row sub-tile
  const bool is_rec = (w < 2);

  __shared__ u16   WhT[WCOL][N_H];     // [n][k], k rotated by 8*n (staging only)
  __shared__ u16   WxT[WCOL][N_H];     // layer0 uses only [.][0..63]
  __shared__ float Cbuf[2][ROWS][WCOL + 1];
  __shared__ u32   sflags[6];          // [0..1] rec-rdy par, [2..3] proj-rdy par, [4..5] pub par
  __shared__ u32   sx[NWG];            // startup: xcc per block
  __shared__ u32   sbar;               // startup barrier result

  u32* arrive = cnt + XBASE;
  u32* xccs   = cnt + XCCS;

  // ---- startup: publish placement, global barrier, deterministic replay ----
  u32 xcc;
  asm volatile("s_getreg_b32 %0, hwreg(HW_REG_XCC_ID)" : "=s"(xcc));
  if (tid == 0) {
    u32* xe = xccs + blockIdx.x;
    u32 xv = xcc & 7u;
    asm volatile("global_store_dword %0, %1, off sc0 sc1\n\ts_waitcnt vmcnt(0)"
                 :: "v"(xe), "v"(xv) : "memory");
    __hip_atomic_fetch_add(arrive, 1u, __ATOMIC_RELAXED, __HIP_MEMORY_SCOPE_AGENT);
    bool bd = false;
    poll_one(arrive, (u32)NWG, &bd);
    sbar = bd ? 1u : 0u;
  }
  if (tid < 6) sflags[tid] = 0;
  __syncthreads();
  const bool bar_dead = (sbar != 0);
  if (!bar_dead && tid < NWG) sx[tid] = rmw_read(xccs + tid) & 7u;
  __syncthreads();

  int bg, layer, j; bool fast;
  if (bar_dead) {
    bg = blockIdx.x & 7;
    int rst = blockIdx.x >> 3;
    layer = rst >> 3; j = rst & 7;
    fast = false;
  } else {
    // replay arrivals: bucket x = the 24 roles of batch-group x. Native
    // claims fill slots 0..23; overflow takes unfilled slots in order.
    u64 c64 = 0;                 // 8x 8-bit native-claim counts (capped at 24)
    int myrid = -1, mypend = -1, pends = 0;
    for (int i = 0; i < NWG; ++i) {
      u32 xv = sx[i];
      u32 c = (u32)((c64 >> (8u * xv)) & 0xffu);
      if (c < 24u) {
        if (i == (int)blockIdx.x) myrid = (int)(xv * 24u + c);
        c64 += (1ull << (8u * xv));
      } else {
        if (i == (int)blockIdx.x) mypend = pends;
        ++pends;
      }
    }
    if (myrid < 0) {
      int p = 0;
      for (int xb = 0; xb < 8; ++xb) {
        u32 c = (u32)((c64 >> (8u * xb)) & 0xffu);
        for (u32 s = c; s < 24u; ++s) {
          if (p == mypend) myrid = xb * 24 + (int)s;
          ++p;
        }
      }
    }
    bg = myrid / 24;
    int slot = myrid % 24;
    layer = slot >> 3; j = slot & 7;
    fast = (((c64 >> (8u * (u32)bg)) & 0xffu) >= 24u);  // all 24 slots native
  }
  const int b = bg;

  const float *Wx, *Wh, *bias; const u16 *in_seq = nullptr; u16 *out_seq;
  if (layer == 0)      { Wx = Wx0; Wh = Wh0; bias = b0; out_seq = seq0; }
  else if (layer == 1) { Wx = Wx1; Wh = Wh1; bias = b1; in_seq = seq0; out_seq = seq1; }
  else                 { Wx = Wx2; Wh = Wh2; bias = b2; in_seq = seq1; out_seq = seq2; }
  const int kin = (layer == 0) ? N_D : N_H;
  u32* cnt_own  = cnt + (size_t)(layer * BG + b) * N_T * CPAD;
  u32* cnt_prev = (layer > 0) ? cnt + (size_t)((layer - 1) * BG + b) * N_T * CPAD : nullptr;

  // Stage weight slices (cols j*64..+64).
  for (int e = tid; e < WCOL * N_H; e += 256) {
    int n = e & 63, k = e >> 6;
    WhT[n][(k + 8 * n) & (N_H - 1)] = f2bf(Wh[k * N_H + j * WCOL + n]);
  }
  for (int e = tid; e < WCOL * kin; e += 256) {
    int n = e & 63, k = e >> 6;
    WxT[n][(k + 8 * n) & (kin - 1)] = f2bf(Wx[k * N_H + j * WCOL + n]);
  }
  float bv[4];
#pragma unroll
  for (int n = 0; n < 4; ++n) bv[n] = bias[j * WCOL + n * 16 + l16];
  __syncthreads();

  // ---- one-time: pull this wave's B fragments from LDS into REGISTERS ----
  // Same array for every role -> single live range. Static indexing (rule #20).
  short8 wf[16][4];
  if (is_rec) {
#pragma unroll
    for (int kt = 0; kt < 16; ++kt)
#pragma unroll
      for (int n = 0; n < 4; ++n) {
        int nl = n * 16 + l16;
        wf[kt][n] = ld8(&WhT[nl][(kt * 32 + quad * 8 + 8 * nl) & (N_H - 1)]);
      }
  } else if (layer == 0) {
#pragma unroll
    for (int n = 0; n < 4; ++n) {
      int nl = n * 16 + l16;
      wf[0][n] = ld8(&WxT[nl][(quad * 8 + 8 * nl) & (N_D - 1)]);
      wf[1][n] = ld8(&WxT[nl][(32 + quad * 8 + 8 * nl) & (N_D - 1)]);
    }
  } else {
#pragma unroll
    for (int kt = 0; kt < 16; ++kt)
#pragma unroll
      for (int n = 0; n < 4; ++n) {
        int nl = n * 16 + l16;
        wf[kt][n] = ld8(&WxT[nl][(kt * 32 + quad * 8 + 8 * nl) & (N_H - 1)]);
      }
  }

  const int arow = b * ROWS + half * 16 + l16;  // this lane's A-row
  bool dead = false;

  for (int t = 0; t < N_T; ++t) {
    const int par = t & 1;
    f32x4 acc[4] = {{0.f,0.f,0.f,0.f},{0.f,0.f,0.f,0.f},{0.f,0.f,0.f,0.f},{0.f,0.f,0.f,0.f}};

    if (!is_rec) {
      // ---- proj waves: (layer0: x_t@Wx) / (else: h_{l-1}(t)@Wx) -> Cbuf ----
      if (layer == 0) {
        const float* xp = x + ((size_t)arow * N_T + t) * N_D + quad * 8;
        short8 f0 = cvt8(xp), f1 = cvt8(xp + 32);
#pragma unroll
        for (int n = 0; n < 4; ++n) {
          acc[n] = MFMA16(f0, wf[0][n], acc[n]);
          acc[n] = MFMA16(f1, wf[1][n], acc[n]);
        }
      } else {
        // ONE poller (w2); w3 spins on LDS flag.
        if (half == 0) {
          if (lane == 0) {
            if (!dead) poll_cnt(cnt_prev + (size_t)t * CPAD, CNT_TGT, fast, &dead);
            lds_set(&sflags[2 + par], (u32)(t + 1));
          }
        } else {
          if (lane == 0 && !dead) lds_wait(&sflags[2 + par], (u32)(t + 1), &dead);
        }
        const u16* sp = in_seq + ((size_t)t * N_B + arow) * N_H + quad * 8;
        i32x4 fr[16];
        if (fast) load16_async_fast(sp, fr);
        else      load16_async_slow(sp, fr);
        K16_PIPE();
      }
      // write proj partials to Cbuf[par]
      int rb = half * 16 + quad * 4;
#pragma unroll
      for (int n = 0; n < 4; ++n)
#pragma unroll
        for (int r = 0; r < 4; ++r)
          Cbuf[par][rb + r][n * 16 + l16] = acc[n][r];
    } else {
      // ---- rec waves: wait own layer t-1 (ONE poller: wave0), load A, h@Wh ----
      if (t > 0) {
        if (half == 0) {
          if (lane == 0) {
            if (!dead) poll_cnt(cnt_own + (size_t)(t - 1) * CPAD, CNT_TGT, fast, &dead);
            lds_set(&sflags[par], (u32)t);
          }
        } else {
          if (lane == 0 && !dead) lds_wait(&sflags[par], (u32)t, &dead);
        }
        const u16* ap = out_seq + ((size_t)(t - 1) * N_B + arow) * N_H + quad * 8;
        i32x4 fr[16];
        if (fast) load16_async_fast(ap, fr);
        else      load16_async_slow(ap, fr);
        K16_PIPE();
      }
    }

    __syncthreads();  // the only per-step barrier: Cbuf[par] ready

    if (is_rec) {
      // ---- combine + tanh + store h; ONE publish per WG ----
      int rb = half * 16 + quad * 4;
      u32 hv[4][4];
#pragma unroll
      for (int n = 0; n < 4; ++n)
#pragma unroll
        for (int r = 0; r < 4; ++r)
          hv[n][r] = (u32)f2bf(fast_tanh(acc[n][r] + Cbuf[par][rb + r][n * 16 + l16] + bv[n]));
      // lane addr: row = b*32 + half*16 + quad*4 (+r), col = j*64 + l16 (+n*16)
      u16* hdst = out_seq + ((size_t)t * N_B + b * ROWS + half * 16 + quad * 4) * N_H
                  + j * WCOL + l16;
      if (fast) {
        asm volatile(
            "global_store_short %0, %1, off sc0\n\t"
            "global_store_short %0, %2, off offset:1024 sc0\n\t"
            "global_store_short %0, %3, off offset:2048 sc0\n\t"
            "global_store_short %0, %4, off offset:3072 sc0\n\t"
            "global_store_short %0, %5, off offset:32 sc0\n\t"
            "global_store_short %0, %6, off offset:1056 sc0\n\t"
            "global_store_short %0, %7, off offset:2080 sc0\n\t"
            "global_store_short %0, %8, off offset:3104 sc0\n\t"
            "global_store_short %0, %9, off offset:64 sc0\n\t"
            "global_store_short %0, %10, off offset:1088 sc0\n\t"
            "global_store_short %0, %11, off offset:2112 sc0\n\t"
            "global_store_short %0, %12, off offset:3136 sc0\n\t"
            "global_store_short %0, %13, off offset:96 sc0\n\t"
            "global_store_short %0, %14, off offset:1120 sc0\n\t"
            "global_store_short %0, %15, off offset:2144 sc0\n\t"
            "global_store_short %0, %16, off offset:3168 sc0"
            :: "v"(hdst),
               "v"(hv[0][0]), "v"(hv[0][1]), "v"(hv[0][2]), "v"(hv[0][3]),
               "v"(hv[1][0]), "v"(hv[1][1]), "v"(hv[1][2]), "v"(hv[1][3]),
               "v"(hv[2][0]), "v"(hv[2][1]), "v"(hv[2][2]), "v"(hv[2][3]),
               "v"(hv[3][0]), "v"(hv[3][1]), "v"(hv[3][2]), "v"(hv[3][3])
            : "memory");
      } else {
        asm volatile(
            "global_store_short %0, %1, off sc0 sc1\n\t"
            "global_store_short %0, %2, off offset:1024 sc0 sc1\n\t"
            "global_store_short %0, %3, off offset:2048 sc0 sc1\n\t"
            "global_store_short %0, %4, off offset:3072 sc0 sc1\n\t"
            "global_store_short %0, %5, off offset:32 sc0 sc1\n\t"
            "global_store_short %0, %6, off offset:1056 sc0 sc1\n\t"
            "global_store_short %0, %7, off offset:2080 sc0 sc1\n\t"
            "global_store_short %0, %8, off offset:3104 sc0 sc1\n\t"
            "global_store_short %0, %9, off offset:64 sc0 sc1\n\t"
            "global_store_short %0, %10, off offset:1088 sc0 sc1\n\t"
            "global_store_short %0, %11, off offset:2112 sc0 sc1\n\t"
            "global_store_short %0, %12, off offset:3136 sc0 sc1\n\t"
            "global_store_short %0, %13, off offset:96 sc0 sc1\n\t"
            "global_store_short %0, %14, off offset:1120 sc0 sc1\n\t"
            "global_store_short %0, %15, off offset:2144 sc0 sc1\n\t"
            "global_store_short %0, %16, off offset:3168 sc0 sc1"
            :: "v"(hdst),
               "v"(hv[0][0]), "v"(hv[0][1]), "v"(hv[0][2]), "v"(hv[0][3]),
               "v"(hv[1][0]), "v"(hv[1][1]), "v"(hv[1][2]), "v"(hv[1][3]),
               "v"(hv[2][0]), "v"(hv[2][1]), "v"(hv[2][2]), "v"(hv[2][3]),
               "v"(hv[3][0]), "v"(hv[3][1]), "v"(hv[3][2]), "v"(hv[3][3])
            : "memory");
      }
      asm volatile("s_waitcnt vmcnt(0)" ::: "memory");  // this wave's stores acked
      if (half == 1) {
        if (lane == 0) lds_set(&sflags[4 + par], (u32)(t + 1));   // wave1 drained
      } else {
        if (lane == 0) {
          if (!dead) lds_wait(&sflags[4 + par], (u32)(t + 1), &dead);  // both drained
          u32* cp = cnt_own + (size_t)t * CPAD;
          if (fast) {
            u32 one = 1u;
            asm volatile("global_atomic_add %0, %1, off" :: "v"(cp), "v"(one) : "memory");
          } else {
            __hip_atomic_fetch_add(cp, 1u, __ATOMIC_RELAXED, __HIP_MEMORY_SCOPE_AGENT);
          }
        }
      }
    }
    // no trailing barrier: Cbuf parity + next barrier handle WAR (r8/r9-proven)
  }
}

// out[b] = seq2[T-1][b][:] . Wf + bf
__global__ void head_kernel(const u16* __restrict__ seq2, const float* __restrict__ Wf,
                            const float* __restrict__ bf, float* __restrict__ out) {
  int b    = blockIdx.x;
  int lane = threadIdx.x;  // 64
  const u16* hrow = seq2 + ((size_t)(N_T - 1) * N_B + b) * N_H;
  float s = 0.f;
#pragma unroll
  for (int r = 0; r < N_H / 64; ++r) {
    int idx = lane * 8 + r;
    s += bf2f(hrow[idx]) * Wf[idx];
  }
#pragma unroll
  for (int off = 32; off > 0; off >>= 1) s += __shfl_down(s, off);
  if (lane == 0) out[b] = s + bf[0];
}

extern "C" void kernel_launch(void* const* d_in, const int* in_sizes, int n_in,
                              void* d_out, int out_size, void* d_ws, size_t ws_size,
                              hipStream_t stream) {
  const float* x   = (const float*)d_in[0];
  const float* Wx0 = (const float*)d_in[1];
  const float* Wh0 = (const float*)d_in[2];
  const float* b0  = (const float*)d_in[3];
  const float* Wx1 = (const float*)d_in[4];
  const float* Wh1 = (const float*)d_in[5];
  const float* b1  = (const float*)d_in[6];
  const float* Wx2 = (const float*)d_in[7];
  const float* Wh2 = (const float*)d_in[8];
  const float* b2  = (const float*)d_in[9];
  const float* Wf  = (const float*)d_in[10];
  const float* bf  = (const float*)d_in[11];
  float* out = (float*)d_out;

  const size_t SEQ_BYTES = (size_t)N_T * N_B * N_H * sizeof(u16);  // 67,108,864
  if (ws_size < 3 * SEQ_BYTES + (size_t)CNT_U32 * sizeof(u32)) return;

  char* ws  = (char*)d_ws;
  u16* seq0 = (u16*)(ws);
  u16* seq1 = (u16*)(ws + SEQ_BYTES);
  u16* seq2 = (u16*)(ws + 2 * SEQ_BYTES);
  u32* cnt  = (u32*)(ws + 3 * SEQ_BYTES);

  (void)hipMemsetAsync(cnt, 0, (size_t)CNT_U32 * sizeof(u32), stream);

  rnn_pipe<<<LAY * BG * CGS, 256, 0, stream>>>(x, Wx0, Wh0, b0, Wx1, Wh1, b1,
                                               Wx2, Wh2, b2, seq0, seq1, seq2,
                                               cnt);
  head_kernel<<<N_B, 64, 0, stream>>>(seq2, Wf, bf, out);
}